// Round 5
// baseline (127.817 us; speedup 1.0000x reference)
//
#include <hip/hip_runtime.h>
#include <hip/hip_bf16.h>
#include <math.h>

#define B_   8
#define C_   192
#define N_   3136
#define K_   9
#define OUT_ 384
#define G_   4
#define CG_  96   // in-channels per group (2C/G)
#define OG_  96   // out-channels per group
#define NTILES 49 // N_/64

typedef __attribute__((ext_vector_type(8))) short short8;
typedef __attribute__((ext_vector_type(4))) float floatx4;
typedef __attribute__((ext_vector_type(3))) unsigned int uintx3;

// ---------------- ws layout (bytes) ----------------
// xT : B*N*C   bf16 =  9,633,792
// wb : OUT*CG  bf16 =     73,728   (stored in MFMA fragment order)
// st : OUT*2   f32  =      3,072   (atomic-accumulated BN stats)
// y  : B*OUT*N bf16 (after st)
static const size_t OFF_XT = 0;
static const size_t OFF_WB = 9633792;
static const size_t OFF_ST = OFF_WB + 73728;

__device__ inline short f2bs(float f) {
    __hip_bfloat16 h = __float2bfloat16(f);
    union { __hip_bfloat16 h; short s; } u; u.h = h; return u.s;
}
__device__ inline float blo(unsigned int u) {
    unsigned int v = u << 16; return __builtin_bit_cast(float, v);
}
__device__ inline float bhi(unsigned int u) {
    unsigned int v = u & 0xffff0000u; return __builtin_bit_cast(float, v);
}
__device__ inline unsigned int packbf(float lo, float hi) {
    unsigned int l = (unsigned int)(unsigned short)f2bs(lo);
    unsigned int h = (unsigned int)(unsigned short)f2bs(hi);
    return (h << 16) | l;
}

// ---- Kernel A: transpose x [B,C,N] f32 -> xT [B,N,C] bf16; W->bf16
//      (written directly in MFMA fragment order); st=0 ----
__global__ __launch_bounds__(256) void k_transpose(const float* __restrict__ x,
                                                   __hip_bfloat16* __restrict__ xT,
                                                   const float* __restrict__ w,
                                                   __hip_bfloat16* __restrict__ wb,
                                                   float* __restrict__ st) {
    // weight conversion + fragment swizzle folded into 144 y==0 blocks.
    // fragment pos within group: (((mt*3+kc)*4+qd)*16+cl)*8 + jj
    //  == (mt*3+kc)*512 + lane*8  for lane=(qd,cl)  -> conv reads 1KB/wave.
    if (blockIdx.y == 0) {
        int j = blockIdx.x * NTILES + blockIdx.z;
        if (j < 144) {
            int i  = j * 256 + threadIdx.x;     // linear index into w[384][96]
            int oc = i / CG_;
            int cg = i - oc * CG_;
            int g  = oc / OG_;
            int ol = oc - g * OG_;
            int mt = ol >> 4, cl = ol & 15;
            int kc = cg >> 5, rem = cg & 31;
            int qd = rem >> 3, jj = rem & 7;
            int pos = (((mt * 3 + kc) * 4 + qd) * 16 + cl) * 8 + jj;
            wb[(size_t)g * (OG_ * CG_) + pos] = __float2bfloat16(w[i]);
        }
    }
    // zero the atomic stats buffer (ws is re-poisoned every iteration)
    if (blockIdx.y == 1 && blockIdx.z == 0 && blockIdx.x == 0) {
        #pragma unroll
        for (int i = 0; i < 3; ++i) st[i * 256 + threadIdx.x] = 0.f;
    }
    __shared__ float tile[64][65];
    int b  = blockIdx.x;
    int cb = blockIdx.y * 64;
    int nb = blockIdx.z * 64;
    int tid = threadIdx.x;
    int tn  = tid & 63;
    int tc4 = tid >> 6;
    const float* xp = x + ((size_t)b * C_ + cb) * N_ + nb;
    #pragma unroll
    for (int i = 0; i < 16; ++i) {
        int c = tc4 + i * 4;
        tile[c][tn] = xp[(size_t)c * N_ + tn];
    }
    __syncthreads();
    __hip_bfloat16* xo = xT + ((size_t)b * N_ + nb) * C_ + cb;
    #pragma unroll
    for (int i = 0; i < 16; ++i) {
        int n = tc4 + i * 4;
        xo[(size_t)n * C_ + tn] = __float2bfloat16(tile[tn][n]);
    }
}

// ---- Kernel C: fused gather + max-rel + grouped conv + atomic BN partials ----
// No weight LDS stage: wb is pre-swizzled in fragment order, so each wave
// reads its wf as one coalesced 1KB global load (L1-resident, 18.4KB/group).
// Deletes the staging loop + one barrier; LDS 38912 -> 20480 B.
__global__ __launch_bounds__(256, 4) void k_conv(const __hip_bfloat16* __restrict__ xT,
                                                 const int* __restrict__ eidx,
                                                 const __hip_bfloat16* __restrict__ Wb,
                                                 __hip_bfloat16* __restrict__ y,
                                                 float* __restrict__ st) {
    int b  = blockIdx.x;
    int g  = blockIdx.y;
    int nt = blockIdx.z;
    int tid  = threadIdx.x;
    int lane = tid & 63;
    int wid  = tid >> 6;
    int n0   = nt * 64 + wid * 16;
    int col  = lane & 15;
    int quad = lane >> 4;

    __shared__ unsigned int xcl[64][50];   // 12,800 B, stride-50 pad
    __shared__ int eL[2][576];             //  4,608 B staged indices
    __shared__ float red[4][192];          //  3,072 B

    // ---- stage edge indices for this tile (coalesced) ----
    {
        const int* e0b = eidx + ((size_t)b * N_ + nt * 64) * K_;
        const int* e1b = eidx + (size_t)B_ * N_ * K_ + ((size_t)b * N_ + nt * 64) * K_;
        for (int e = tid; e < 576; e += 256) {
            eL[0][e] = e0b[e];
            eL[1][e] = e1b[e];
        }
    }
    __syncthreads();

    // ---- fused gather + max-relative into LDS xc tile ----
    // 8 lanes/node, each lane owns 3 consecutive dwords of the 24-dword slice.
    int lane8 = tid & 7;
    int slot  = tid >> 3;              // 0..31
    const unsigned int* xb =
        reinterpret_cast<const unsigned int*>(xT + (size_t)b * N_ * C_);
    int cbase = 24 * g + 3 * lane8;
    #pragma unroll
    for (int p = 0; p < 2; ++p) {
        int nloc = p * 32 + slot;      // node within tile, 0..63
        int n    = nt * 64 + nloc;
        // hoist all index reads, then batch-issue all scattered loads
        int a0[K_], a1[K_];
        #pragma unroll
        for (int k = 0; k < K_; ++k) {
            a0[k] = eL[0][nloc * 9 + k] * 96 + cbase;
            a1[k] = eL[1][nloc * 9 + k] * 96 + cbase;
        }
        uintx3 ctr = *reinterpret_cast<const uintx3*>(xb + (size_t)n * 96 + cbase);
        uintx3 vj[K_], vi[K_];
        #pragma unroll
        for (int k = 0; k < K_; ++k)
            vj[k] = *reinterpret_cast<const uintx3*>(xb + (size_t)a0[k]);
        #pragma unroll
        for (int k = 0; k < K_; ++k)
            vi[k] = *reinterpret_cast<const uintx3*>(xb + (size_t)a1[k]);
        float m0 = -INFINITY, m1 = -INFINITY, m2 = -INFINITY;
        float m3 = -INFINITY, m4 = -INFINITY, m5 = -INFINITY;
        #pragma unroll
        for (int k = 0; k < K_; ++k) {
            m0 = fmaxf(m0, blo(vj[k].x) - blo(vi[k].x));
            m1 = fmaxf(m1, bhi(vj[k].x) - bhi(vi[k].x));
            m2 = fmaxf(m2, blo(vj[k].y) - blo(vi[k].y));
            m3 = fmaxf(m3, bhi(vj[k].y) - bhi(vi[k].y));
            m4 = fmaxf(m4, blo(vj[k].z) - blo(vi[k].z));
            m5 = fmaxf(m5, bhi(vj[k].z) - bhi(vi[k].z));
        }
        unsigned int* orow = &xcl[nloc][6 * lane8];
        uint2 w0, w1, w2;
        w0.x = packbf(blo(ctr.x), m0); w0.y = packbf(bhi(ctr.x), m1);
        w1.x = packbf(blo(ctr.y), m2); w1.y = packbf(bhi(ctr.y), m3);
        w2.x = packbf(blo(ctr.z), m4); w2.y = packbf(bhi(ctr.z), m5);
        reinterpret_cast<uint2*>(orow)[0] = w0;
        reinterpret_cast<uint2*>(orow)[1] = w1;
        reinterpret_cast<uint2*>(orow)[2] = w2;
    }
    __syncthreads();

    // ---- MFMA: A=weights straight from fragment-ordered global (L1),
    //      B=xc fragments from LDS. No bias (cancels under batch-stat BN) ----
    const short* Wg = reinterpret_cast<const short*>(Wb) + (size_t)g * (OG_ * CG_);
    floatx4 acc[6];
    #pragma unroll
    for (int mt = 0; mt < 6; ++mt) acc[mt] = (floatx4){0.f, 0.f, 0.f, 0.f};
    #pragma unroll
    for (int kc = 0; kc < 3; ++kc) {
        short8 xf = *reinterpret_cast<const short8*>(
            &xcl[wid * 16 + col][kc * 16 + quad * 4]);
        #pragma unroll
        for (int mt = 0; mt < 6; ++mt) {
            short8 wf = *reinterpret_cast<const short8*>(
                Wg + (mt * 3 + kc) * 512 + lane * 8);
            acc[mt] = __builtin_amdgcn_mfma_f32_16x16x32_bf16(wf, xf, acc[mt], 0, 0, 0);
        }
    }

    // D layout: col(n) = lane&15, row(oc) = quad*4 + reg
    #pragma unroll
    for (int mt = 0; mt < 6; ++mt) {
        #pragma unroll
        for (int r = 0; r < 4; ++r) {
            int ol = mt * 16 + quad * 4 + r;     // oc within group, 0..95
            int oc = g * OG_ + ol;
            float v = acc[mt][r];
            y[((size_t)b * OUT_ + oc) * N_ + n0 + col] = __float2bfloat16(v);
            float s = v, ss = v * v;
            #pragma unroll
            for (int m = 1; m <= 8; m <<= 1) {
                s  += __shfl_xor(s, m);
                ss += __shfl_xor(ss, m);
            }
            if (col == 0) {
                red[wid][ol]      = s;
                red[wid][96 + ol] = ss;
            }
        }
    }
    __syncthreads();
    if (tid < 192) {
        float t = red[0][tid] + red[1][tid] + red[2][tid] + red[3][tid];
        if (tid < 96) atomicAdd(&st[g * OG_ + tid], t);
        else          atomicAdd(&st[OUT_ + g * OG_ + (tid - 96)], t);
    }
}

// ---- Kernel E: BN (batch stats) + exact GELU, 8 elems/thread ----
__global__ __launch_bounds__(256) void k_bn_gelu(const __hip_bfloat16* __restrict__ y,
                                                 const float* __restrict__ st,
                                                 const float* __restrict__ gamma,
                                                 const float* __restrict__ beta,
                                                 float* __restrict__ out) {
    size_t base = ((size_t)blockIdx.x * 256 + threadIdx.x) * 8;
    int oc = (int)((base / N_) % OUT_);       // N_ % 8 == 0 -> uniform oc per 8
    const float invM = 1.0f / (float)(B_ * N_);
    float s = st[oc], ss = st[OUT_ + oc];
    float mean = s * invM;
    float var  = ss * invM - mean * mean;
    float inv  = 1.0f / sqrtf(var + 1e-5f);
    float sc = gamma[oc] * inv;
    float sh = beta[oc] - mean * sc;

    short8 v8 = *reinterpret_cast<const short8*>(y + base);
    float4 o0, o1;
    float* op0 = &o0.x;
    float* op1 = &o1.x;
    #pragma unroll
    for (int j = 0; j < 8; ++j) {
        unsigned int u = ((unsigned int)(unsigned short)v8[j]) << 16;
        float t = __builtin_bit_cast(float, u) * sc + sh;
        float r = 0.5f * t * (1.0f + erff(t * 0.70710678118654752f));
        if (j < 4) op0[j] = r; else op1[j - 4] = r;
    }
    *reinterpret_cast<float4*>(out + base)     = o0;
    *reinterpret_cast<float4*>(out + base + 4) = o1;
}

extern "C" void kernel_launch(void* const* d_in, const int* in_sizes, int n_in,
                              void* d_out, int out_size, void* d_ws, size_t ws_size,
                              hipStream_t stream) {
    const float* x      = (const float*)d_in[0];
    const int*   eidx   = (const int*)d_in[1];
    const float* conv_w = (const float*)d_in[2];
    // d_in[3] = conv_b: unused (bias cancels exactly under batch-stat BN)
    const float* gamma  = (const float*)d_in[4];
    const float* beta   = (const float*)d_in[5];
    float* out = (float*)d_out;

    char* ws = (char*)d_ws;
    __hip_bfloat16* xT = (__hip_bfloat16*)(ws + OFF_XT);
    __hip_bfloat16* wb = (__hip_bfloat16*)(ws + OFF_WB);
    float*          st = (float*)(ws + OFF_ST);
    __hip_bfloat16* y  = (__hip_bfloat16*)(ws + OFF_ST + 3072);

    k_transpose<<<dim3(B_, C_ / 64, N_ / 64), 256, 0, stream>>>(x, xT, conv_w, wb, st);
    k_conv<<<dim3(B_, G_, NTILES), 256, 0, stream>>>(xT, eidx, wb, y, st);
    k_bn_gelu<<<dim3((B_ * OUT_ * N_) / (256 * 8)), 256, 0, stream>>>(y, st, gamma, beta, out);
}

// Round 6
// 127.104 us; speedup vs baseline: 1.0056x; 1.0056x over previous
//
#include <hip/hip_runtime.h>
#include <hip/hip_bf16.h>
#include <math.h>

#define B_   8
#define C_   192
#define N_   3136
#define K_   9
#define OUT_ 384
#define G_   4
#define CG_  96   // in-channels per group (2C/G)
#define OG_  96   // out-channels per group
#define NTILES 49 // N_/64

typedef __attribute__((ext_vector_type(8))) short short8;
typedef __attribute__((ext_vector_type(4))) float floatx4;
typedef __attribute__((ext_vector_type(3))) unsigned int uintx3;

// ---------------- ws layout (bytes) ----------------
// xT : B*N*C   bf16 =  9,633,792
// wb : OUT*CG  bf16 =     73,728
// st : OUT*2   f32  =      3,072   (atomic-accumulated BN stats)
// y  : B*OUT*N bf16 (after st)
static const size_t OFF_XT = 0;
static const size_t OFF_WB = 9633792;
static const size_t OFF_ST = OFF_WB + 73728;

__device__ inline short f2bs(float f) {
    __hip_bfloat16 h = __float2bfloat16(f);
    union { __hip_bfloat16 h; short s; } u; u.h = h; return u.s;
}
__device__ inline float blo(unsigned int u) {
    unsigned int v = u << 16; return __builtin_bit_cast(float, v);
}
__device__ inline float bhi(unsigned int u) {
    unsigned int v = u & 0xffff0000u; return __builtin_bit_cast(float, v);
}
__device__ inline unsigned int packbf(float lo, float hi) {
    unsigned int l = (unsigned int)(unsigned short)f2bs(lo);
    unsigned int h = (unsigned int)(unsigned short)f2bs(hi);
    return (h << 16) | l;
}

// ---- Kernel A: transpose x [B,C,N] f32 -> xT [B,N,C] bf16; W->bf16; st=0 ----
__global__ __launch_bounds__(256) void k_transpose(const float* __restrict__ x,
                                                   __hip_bfloat16* __restrict__ xT,
                                                   const float* __restrict__ w,
                                                   __hip_bfloat16* __restrict__ wb,
                                                   float* __restrict__ st) {
    // weight conversion folded into 144 of the 392 y==0 blocks
    if (blockIdx.y == 0) {
        int j = blockIdx.x * NTILES + blockIdx.z;
        if (j < 144) {
            int i = j * 256 + threadIdx.x;
            wb[i] = __float2bfloat16(w[i]);
        }
    }
    // zero the atomic stats buffer (ws is re-poisoned every iteration)
    if (blockIdx.y == 1 && blockIdx.z == 0 && blockIdx.x == 0) {
        #pragma unroll
        for (int i = 0; i < 3; ++i) st[i * 256 + threadIdx.x] = 0.f;
    }
    __shared__ float tile[64][65];
    int b  = blockIdx.x;
    int cb = blockIdx.y * 64;
    int nb = blockIdx.z * 64;
    int tid = threadIdx.x;
    int tn  = tid & 63;
    int tc4 = tid >> 6;
    const float* xp = x + ((size_t)b * C_ + cb) * N_ + nb;
    #pragma unroll
    for (int i = 0; i < 16; ++i) {
        int c = tc4 + i * 4;
        tile[c][tn] = xp[(size_t)c * N_ + tn];
    }
    __syncthreads();
    __hip_bfloat16* xo = xT + ((size_t)b * N_ + nb) * C_ + cb;
    #pragma unroll
    for (int i = 0; i < 16; ++i) {
        int n = tc4 + i * 4;
        xo[(size_t)n * C_ + tn] = __float2bfloat16(tile[tn][n]);
    }
}

// ---- Kernel C: fused gather + max-rel + grouped conv + atomic BN partials ----
// Grid is (nt, g, b): batch is SLOWEST-varying, so the round-robin
// workgroup->XCD assignment gives each XCD a window of ~1-2 batches; the
// random neighbor gather then hits that batch's 1.2 MB xT slice in the
// XCD-local 4 MB L2 instead of thrashing 8 batches (9.6 MB) through L3.
// LDS kept at 38,912 B (4 blocks/CU) -- R5 showed that shrinking LDS makes
// the scheduler target 8 blocks/CU (64-VGPR budget) and serialize the
// gather loads (VGPR=40, conv 48us vs R4's <43.4us).
__global__ __launch_bounds__(256, 4) void k_conv(const __hip_bfloat16* __restrict__ xT,
                                                 const int* __restrict__ eidx,
                                                 const __hip_bfloat16* __restrict__ Wb,
                                                 __hip_bfloat16* __restrict__ y,
                                                 float* __restrict__ st) {
    int nt = blockIdx.x;
    int g  = blockIdx.y;
    int b  = blockIdx.z;
    int tid  = threadIdx.x;
    int lane = tid & 63;
    int wid  = tid >> 6;
    int n0   = nt * 64 + wid * 16;
    int col  = lane & 15;
    int quad = lane >> 4;

    __shared__ short wl[OG_ * CG_];        // 18,432 B, fragment-order swizzled
    __shared__ unsigned int xcl[64][50];   // 12,800 B, stride-50 pad
    __shared__ int eL[2][576];             //  4,608 B staged indices
    __shared__ float red[4][192];          //  3,072 B

    // ---- stage group-g weights: coalesced uint2 -> fragment-swizzled LDS ----
    const uint2* src = reinterpret_cast<const uint2*>(Wb + (size_t)g * OG_ * CG_);
    #pragma unroll
    for (int it = 0; it < 9; ++it) {
        int i  = it * 256 + tid;      // uint2 index, 2304 total
        uint2 v = src[i];
        int gs = i * 4;
        int oc = gs / CG_;
        int cg = gs - oc * CG_;
        int mt = oc >> 4, cl = oc & 15;
        int kc = cg >> 5, rem = cg & 31;
        int qd = rem >> 3, j = rem & 7;   // j in {0,4}
        int pos = (((mt * 3 + kc) * 4 + qd) * 16 + cl) * 8 + j;
        *reinterpret_cast<uint2*>(&wl[pos]) = v;
    }

    // ---- stage edge indices for this tile (coalesced) ----
    {
        const int* e0b = eidx + ((size_t)b * N_ + nt * 64) * K_;
        const int* e1b = eidx + (size_t)B_ * N_ * K_ + ((size_t)b * N_ + nt * 64) * K_;
        for (int e = tid; e < 576; e += 256) {
            eL[0][e] = e0b[e];
            eL[1][e] = e1b[e];
        }
    }
    __syncthreads();

    // ---- fused gather + max-relative into LDS xc tile ----
    // 8 lanes/node, each lane owns 3 consecutive dwords of the 24-dword slice.
    int lane8 = tid & 7;
    int slot  = tid >> 3;              // 0..31
    const unsigned int* xb =
        reinterpret_cast<const unsigned int*>(xT + (size_t)b * N_ * C_);
    int cbase = 24 * g + 3 * lane8;
    #pragma unroll
    for (int p = 0; p < 2; ++p) {
        int nloc = p * 32 + slot;      // node within tile, 0..63
        int n    = nt * 64 + nloc;
        // hoist all index reads, then batch-issue all scattered loads
        int a0[K_], a1[K_];
        #pragma unroll
        for (int k = 0; k < K_; ++k) {
            a0[k] = eL[0][nloc * 9 + k] * 96 + cbase;
            a1[k] = eL[1][nloc * 9 + k] * 96 + cbase;
        }
        uintx3 ctr = *reinterpret_cast<const uintx3*>(xb + (size_t)n * 96 + cbase);
        uintx3 vj[K_], vi[K_];
        #pragma unroll
        for (int k = 0; k < K_; ++k)
            vj[k] = *reinterpret_cast<const uintx3*>(xb + (size_t)a0[k]);
        #pragma unroll
        for (int k = 0; k < K_; ++k)
            vi[k] = *reinterpret_cast<const uintx3*>(xb + (size_t)a1[k]);
        float m0 = -INFINITY, m1 = -INFINITY, m2 = -INFINITY;
        float m3 = -INFINITY, m4 = -INFINITY, m5 = -INFINITY;
        #pragma unroll
        for (int k = 0; k < K_; ++k) {
            m0 = fmaxf(m0, blo(vj[k].x) - blo(vi[k].x));
            m1 = fmaxf(m1, bhi(vj[k].x) - bhi(vi[k].x));
            m2 = fmaxf(m2, blo(vj[k].y) - blo(vi[k].y));
            m3 = fmaxf(m3, bhi(vj[k].y) - bhi(vi[k].y));
            m4 = fmaxf(m4, blo(vj[k].z) - blo(vi[k].z));
            m5 = fmaxf(m5, bhi(vj[k].z) - bhi(vi[k].z));
        }
        unsigned int* orow = &xcl[nloc][6 * lane8];
        uint2 w0, w1, w2;
        w0.x = packbf(blo(ctr.x), m0); w0.y = packbf(bhi(ctr.x), m1);
        w1.x = packbf(blo(ctr.y), m2); w1.y = packbf(bhi(ctr.y), m3);
        w2.x = packbf(blo(ctr.z), m4); w2.y = packbf(bhi(ctr.z), m5);
        reinterpret_cast<uint2*>(orow)[0] = w0;
        reinterpret_cast<uint2*>(orow)[1] = w1;
        reinterpret_cast<uint2*>(orow)[2] = w2;
    }
    __syncthreads();

    // ---- MFMA from LDS (no bias: it cancels exactly under batch-stat BN) ----
    floatx4 acc[6];
    #pragma unroll
    for (int mt = 0; mt < 6; ++mt) acc[mt] = (floatx4){0.f, 0.f, 0.f, 0.f};
    #pragma unroll
    for (int kc = 0; kc < 3; ++kc) {
        short8 xf = *reinterpret_cast<const short8*>(
            &xcl[wid * 16 + col][kc * 16 + quad * 4]);
        #pragma unroll
        for (int mt = 0; mt < 6; ++mt) {
            short8 wf = *reinterpret_cast<const short8*>(
                &wl[(((mt * 3 + kc) * 4 + quad) * 16 + col) * 8]);
            acc[mt] = __builtin_amdgcn_mfma_f32_16x16x32_bf16(wf, xf, acc[mt], 0, 0, 0);
        }
    }

    // D layout: col(n) = lane&15, row(oc) = quad*4 + reg
    #pragma unroll
    for (int mt = 0; mt < 6; ++mt) {
        #pragma unroll
        for (int r = 0; r < 4; ++r) {
            int ol = mt * 16 + quad * 4 + r;     // oc within group, 0..95
            int oc = g * OG_ + ol;
            float v = acc[mt][r];
            y[((size_t)b * OUT_ + oc) * N_ + n0 + col] = __float2bfloat16(v);
            float s = v, ss = v * v;
            #pragma unroll
            for (int m = 1; m <= 8; m <<= 1) {
                s  += __shfl_xor(s, m);
                ss += __shfl_xor(ss, m);
            }
            if (col == 0) {
                red[wid][ol]      = s;
                red[wid][96 + ol] = ss;
            }
        }
    }
    __syncthreads();
    if (tid < 192) {
        float t = red[0][tid] + red[1][tid] + red[2][tid] + red[3][tid];
        if (tid < 96) atomicAdd(&st[g * OG_ + tid], t);
        else          atomicAdd(&st[OUT_ + g * OG_ + (tid - 96)], t);
    }
}

// ---- Kernel E: BN (batch stats) + exact GELU, 8 elems/thread ----
__global__ __launch_bounds__(256) void k_bn_gelu(const __hip_bfloat16* __restrict__ y,
                                                 const float* __restrict__ st,
                                                 const float* __restrict__ gamma,
                                                 const float* __restrict__ beta,
                                                 float* __restrict__ out) {
    size_t base = ((size_t)blockIdx.x * 256 + threadIdx.x) * 8;
    int oc = (int)((base / N_) % OUT_);       // N_ % 8 == 0 -> uniform oc per 8
    const float invM = 1.0f / (float)(B_ * N_);
    float s = st[oc], ss = st[OUT_ + oc];
    float mean = s * invM;
    float var  = ss * invM - mean * mean;
    float inv  = 1.0f / sqrtf(var + 1e-5f);
    float sc = gamma[oc] * inv;
    float sh = beta[oc] - mean * sc;

    short8 v8 = *reinterpret_cast<const short8*>(y + base);
    float4 o0, o1;
    float* op0 = &o0.x;
    float* op1 = &o1.x;
    #pragma unroll
    for (int j = 0; j < 8; ++j) {
        unsigned int u = ((unsigned int)(unsigned short)v8[j]) << 16;
        float t = __builtin_bit_cast(float, u) * sc + sh;
        float r = 0.5f * t * (1.0f + erff(t * 0.70710678118654752f));
        if (j < 4) op0[j] = r; else op1[j - 4] = r;
    }
    *reinterpret_cast<float4*>(out + base)     = o0;
    *reinterpret_cast<float4*>(out + base + 4) = o1;
}

extern "C" void kernel_launch(void* const* d_in, const int* in_sizes, int n_in,
                              void* d_out, int out_size, void* d_ws, size_t ws_size,
                              hipStream_t stream) {
    const float* x      = (const float*)d_in[0];
    const int*   eidx   = (const int*)d_in[1];
    const float* conv_w = (const float*)d_in[2];
    // d_in[3] = conv_b: unused (bias cancels exactly under batch-stat BN)
    const float* gamma  = (const float*)d_in[4];
    const float* beta   = (const float*)d_in[5];
    float* out = (float*)d_out;

    char* ws = (char*)d_ws;
    __hip_bfloat16* xT = (__hip_bfloat16*)(ws + OFF_XT);
    __hip_bfloat16* wb = (__hip_bfloat16*)(ws + OFF_WB);
    float*          st = (float*)(ws + OFF_ST);
    __hip_bfloat16* y  = (__hip_bfloat16*)(ws + OFF_ST + 3072);

    k_transpose<<<dim3(B_, C_ / 64, N_ / 64), 256, 0, stream>>>(x, xT, conv_w, wb, st);
    k_conv<<<dim3(NTILES, G_, B_), 256, 0, stream>>>(xT, eidx, wb, y, st);
    k_bn_gelu<<<dim3((B_ * OUT_ * N_) / (256 * 8)), 256, 0, stream>>>(y, st, gamma, beta, out);
}

// Round 7
// 125.534 us; speedup vs baseline: 1.0182x; 1.0125x over previous
//
#include <hip/hip_runtime.h>
#include <hip/hip_bf16.h>
#include <math.h>

#define B_   8
#define C_   192
#define N_   3136
#define K_   9
#define OUT_ 384
#define G_   4
#define CG_  96   // in-channels per group (2C/G)
#define OG_  96   // out-channels per group
#define NTILES 49 // N_/64

typedef __attribute__((ext_vector_type(8))) short short8;
typedef __attribute__((ext_vector_type(4))) float floatx4;
typedef __attribute__((ext_vector_type(3))) unsigned int uintx3;

// ---------------- ws layout (bytes) ----------------
// xT : B*N*C   bf16 =  9,633,792
// wb : OUT*CG  bf16 =     73,728
// st : OUT*2   f32  =      3,072   (atomic-accumulated BN stats)
// y  : B*OUT*N bf16 (after st)
static const size_t OFF_XT = 0;
static const size_t OFF_WB = 9633792;
static const size_t OFF_ST = OFF_WB + 73728;

__device__ inline short f2bs(float f) {
    __hip_bfloat16 h = __float2bfloat16(f);
    union { __hip_bfloat16 h; short s; } u; u.h = h; return u.s;
}
__device__ inline float blo(unsigned int u) {
    unsigned int v = u << 16; return __builtin_bit_cast(float, v);
}
__device__ inline float bhi(unsigned int u) {
    unsigned int v = u & 0xffff0000u; return __builtin_bit_cast(float, v);
}
__device__ inline unsigned int packbf(float lo, float hi) {
    unsigned int l = (unsigned int)(unsigned short)f2bs(lo);
    unsigned int h = (unsigned int)(unsigned short)f2bs(hi);
    return (h << 16) | l;
}

// ---- Kernel A: transpose x [B,C,N] f32 -> xT [B,N,C] bf16; W->bf16; st=0 ----
__global__ __launch_bounds__(256) void k_transpose(const float* __restrict__ x,
                                                   __hip_bfloat16* __restrict__ xT,
                                                   const float* __restrict__ w,
                                                   __hip_bfloat16* __restrict__ wb,
                                                   float* __restrict__ st) {
    // weight conversion folded into 144 of the 392 y==0 blocks
    if (blockIdx.y == 0) {
        int j = blockIdx.x * NTILES + blockIdx.z;
        if (j < 144) {
            int i = j * 256 + threadIdx.x;
            wb[i] = __float2bfloat16(w[i]);
        }
    }
    // zero the atomic stats buffer (ws is re-poisoned every iteration)
    if (blockIdx.y == 1 && blockIdx.z == 0 && blockIdx.x == 0) {
        #pragma unroll
        for (int i = 0; i < 3; ++i) st[i * 256 + threadIdx.x] = 0.f;
    }
    __shared__ float tile[64][65];
    int b  = blockIdx.x;
    int cb = blockIdx.y * 64;
    int nb = blockIdx.z * 64;
    int tid = threadIdx.x;
    int tn  = tid & 63;
    int tc4 = tid >> 6;
    const float* xp = x + ((size_t)b * C_ + cb) * N_ + nb;
    #pragma unroll
    for (int i = 0; i < 16; ++i) {
        int c = tc4 + i * 4;
        tile[c][tn] = xp[(size_t)c * N_ + tn];
    }
    __syncthreads();
    __hip_bfloat16* xo = xT + ((size_t)b * N_ + nb) * C_ + cb;
    #pragma unroll
    for (int i = 0; i < 16; ++i) {
        int n = tc4 + i * 4;
        xo[(size_t)n * C_ + tn] = __float2bfloat16(tile[tn][n]);
    }
}

// ---- Kernel C: fused gather + max-rel + grouped conv + atomic BN partials ----
// R4 config (measured best: 123.9us): grid (b,g,nt), wl in LDS, bounds(256,4).
// NEW: sched_barrier(0) between the gather-load cluster and the fmax loop.
// R5 proved the compiler sinks the batched loads back to their uses
// (VGPR=40), leaving ~4 loads in flight and paying L2/L3 latency ~5x per
// pass. The barrier pins all 19 loads above / all uses below: one latency
// exposure per pass. Expected VGPR ~90-120 (the assert that it worked).
__global__ __launch_bounds__(256, 4) void k_conv(const __hip_bfloat16* __restrict__ xT,
                                                 const int* __restrict__ eidx,
                                                 const __hip_bfloat16* __restrict__ Wb,
                                                 __hip_bfloat16* __restrict__ y,
                                                 float* __restrict__ st) {
    int b  = blockIdx.x;
    int g  = blockIdx.y;
    int nt = blockIdx.z;
    int tid  = threadIdx.x;
    int lane = tid & 63;
    int wid  = tid >> 6;
    int n0   = nt * 64 + wid * 16;
    int col  = lane & 15;
    int quad = lane >> 4;

    __shared__ short wl[OG_ * CG_];        // 18,432 B, fragment-order swizzled
    __shared__ unsigned int xcl[64][50];   // 12,800 B, stride-50 pad
    __shared__ int eL[2][576];             //  4,608 B staged indices
    __shared__ float red[4][192];          //  3,072 B

    // ---- stage group-g weights: coalesced uint2 -> fragment-swizzled LDS ----
    const uint2* src = reinterpret_cast<const uint2*>(Wb + (size_t)g * OG_ * CG_);
    #pragma unroll
    for (int it = 0; it < 9; ++it) {
        int i  = it * 256 + tid;      // uint2 index, 2304 total
        uint2 v = src[i];
        int gs = i * 4;
        int oc = gs / CG_;
        int cg = gs - oc * CG_;
        int mt = oc >> 4, cl = oc & 15;
        int kc = cg >> 5, rem = cg & 31;
        int qd = rem >> 3, j = rem & 7;   // j in {0,4}
        int pos = (((mt * 3 + kc) * 4 + qd) * 16 + cl) * 8 + j;
        *reinterpret_cast<uint2*>(&wl[pos]) = v;
    }

    // ---- stage edge indices for this tile (coalesced) ----
    {
        const int* e0b = eidx + ((size_t)b * N_ + nt * 64) * K_;
        const int* e1b = eidx + (size_t)B_ * N_ * K_ + ((size_t)b * N_ + nt * 64) * K_;
        for (int e = tid; e < 576; e += 256) {
            eL[0][e] = e0b[e];
            eL[1][e] = e1b[e];
        }
    }
    __syncthreads();

    // ---- fused gather + max-relative into LDS xc tile ----
    // 8 lanes/node, each lane owns 3 consecutive dwords of the 24-dword slice.
    int lane8 = tid & 7;
    int slot  = tid >> 3;              // 0..31
    const unsigned int* xb =
        reinterpret_cast<const unsigned int*>(xT + (size_t)b * N_ * C_);
    int cbase = 24 * g + 3 * lane8;
    #pragma unroll
    for (int p = 0; p < 2; ++p) {
        int nloc = p * 32 + slot;      // node within tile, 0..63
        int n    = nt * 64 + nloc;
        // hoist all index reads, then batch-issue all scattered loads
        int a0[K_], a1[K_];
        #pragma unroll
        for (int k = 0; k < K_; ++k) {
            a0[k] = eL[0][nloc * 9 + k] * 96 + cbase;
            a1[k] = eL[1][nloc * 9 + k] * 96 + cbase;
        }
        uintx3 ctr = *reinterpret_cast<const uintx3*>(xb + (size_t)n * 96 + cbase);
        uintx3 vj[K_], vi[K_];
        #pragma unroll
        for (int k = 0; k < K_; ++k)
            vj[k] = *reinterpret_cast<const uintx3*>(xb + (size_t)a0[k]);
        #pragma unroll
        for (int k = 0; k < K_; ++k)
            vi[k] = *reinterpret_cast<const uintx3*>(xb + (size_t)a1[k]);
        // pin: all 19 loads issue above this line; all consumers stay below.
        __builtin_amdgcn_sched_barrier(0);
        float m0 = -INFINITY, m1 = -INFINITY, m2 = -INFINITY;
        float m3 = -INFINITY, m4 = -INFINITY, m5 = -INFINITY;
        #pragma unroll
        for (int k = 0; k < K_; ++k) {
            m0 = fmaxf(m0, blo(vj[k].x) - blo(vi[k].x));
            m1 = fmaxf(m1, bhi(vj[k].x) - bhi(vi[k].x));
            m2 = fmaxf(m2, blo(vj[k].y) - blo(vi[k].y));
            m3 = fmaxf(m3, bhi(vj[k].y) - bhi(vi[k].y));
            m4 = fmaxf(m4, blo(vj[k].z) - blo(vi[k].z));
            m5 = fmaxf(m5, bhi(vj[k].z) - bhi(vi[k].z));
        }
        unsigned int* orow = &xcl[nloc][6 * lane8];
        uint2 w0, w1, w2;
        w0.x = packbf(blo(ctr.x), m0); w0.y = packbf(bhi(ctr.x), m1);
        w1.x = packbf(blo(ctr.y), m2); w1.y = packbf(bhi(ctr.y), m3);
        w2.x = packbf(blo(ctr.z), m4); w2.y = packbf(bhi(ctr.z), m5);
        reinterpret_cast<uint2*>(orow)[0] = w0;
        reinterpret_cast<uint2*>(orow)[1] = w1;
        reinterpret_cast<uint2*>(orow)[2] = w2;
    }
    __syncthreads();

    // ---- MFMA from LDS (no bias: it cancels exactly under batch-stat BN) ----
    floatx4 acc[6];
    #pragma unroll
    for (int mt = 0; mt < 6; ++mt) acc[mt] = (floatx4){0.f, 0.f, 0.f, 0.f};
    #pragma unroll
    for (int kc = 0; kc < 3; ++kc) {
        short8 xf = *reinterpret_cast<const short8*>(
            &xcl[wid * 16 + col][kc * 16 + quad * 4]);
        #pragma unroll
        for (int mt = 0; mt < 6; ++mt) {
            short8 wf = *reinterpret_cast<const short8*>(
                &wl[(((mt * 3 + kc) * 4 + quad) * 16 + col) * 8]);
            acc[mt] = __builtin_amdgcn_mfma_f32_16x16x32_bf16(wf, xf, acc[mt], 0, 0, 0);
        }
    }

    // D layout: col(n) = lane&15, row(oc) = quad*4 + reg
    #pragma unroll
    for (int mt = 0; mt < 6; ++mt) {
        #pragma unroll
        for (int r = 0; r < 4; ++r) {
            int ol = mt * 16 + quad * 4 + r;     // oc within group, 0..95
            int oc = g * OG_ + ol;
            float v = acc[mt][r];
            y[((size_t)b * OUT_ + oc) * N_ + n0 + col] = __float2bfloat16(v);
            float s = v, ss = v * v;
            #pragma unroll
            for (int m = 1; m <= 8; m <<= 1) {
                s  += __shfl_xor(s, m);
                ss += __shfl_xor(ss, m);
            }
            if (col == 0) {
                red[wid][ol]      = s;
                red[wid][96 + ol] = ss;
            }
        }
    }
    __syncthreads();
    if (tid < 192) {
        float t = red[0][tid] + red[1][tid] + red[2][tid] + red[3][tid];
        if (tid < 96) atomicAdd(&st[g * OG_ + tid], t);
        else          atomicAdd(&st[OUT_ + g * OG_ + (tid - 96)], t);
    }
}

// ---- Kernel E: BN (batch stats) + exact GELU, 8 elems/thread ----
__global__ __launch_bounds__(256) void k_bn_gelu(const __hip_bfloat16* __restrict__ y,
                                                 const float* __restrict__ st,
                                                 const float* __restrict__ gamma,
                                                 const float* __restrict__ beta,
                                                 float* __restrict__ out) {
    size_t base = ((size_t)blockIdx.x * 256 + threadIdx.x) * 8;
    int oc = (int)((base / N_) % OUT_);       // N_ % 8 == 0 -> uniform oc per 8
    const float invM = 1.0f / (float)(B_ * N_);
    float s = st[oc], ss = st[OUT_ + oc];
    float mean = s * invM;
    float var  = ss * invM - mean * mean;
    float inv  = 1.0f / sqrtf(var + 1e-5f);
    float sc = gamma[oc] * inv;
    float sh = beta[oc] - mean * sc;

    short8 v8 = *reinterpret_cast<const short8*>(y + base);
    float4 o0, o1;
    float* op0 = &o0.x;
    float* op1 = &o1.x;
    #pragma unroll
    for (int j = 0; j < 8; ++j) {
        unsigned int u = ((unsigned int)(unsigned short)v8[j]) << 16;
        float t = __builtin_bit_cast(float, u) * sc + sh;
        float r = 0.5f * t * (1.0f + erff(t * 0.70710678118654752f));
        if (j < 4) op0[j] = r; else op1[j - 4] = r;
    }
    *reinterpret_cast<float4*>(out + base)     = o0;
    *reinterpret_cast<float4*>(out + base + 4) = o1;
}

extern "C" void kernel_launch(void* const* d_in, const int* in_sizes, int n_in,
                              void* d_out, int out_size, void* d_ws, size_t ws_size,
                              hipStream_t stream) {
    const float* x      = (const float*)d_in[0];
    const int*   eidx   = (const int*)d_in[1];
    const float* conv_w = (const float*)d_in[2];
    // d_in[3] = conv_b: unused (bias cancels exactly under batch-stat BN)
    const float* gamma  = (const float*)d_in[4];
    const float* beta   = (const float*)d_in[5];
    float* out = (float*)d_out;

    char* ws = (char*)d_ws;
    __hip_bfloat16* xT = (__hip_bfloat16*)(ws + OFF_XT);
    __hip_bfloat16* wb = (__hip_bfloat16*)(ws + OFF_WB);
    float*          st = (float*)(ws + OFF_ST);
    __hip_bfloat16* y  = (__hip_bfloat16*)(ws + OFF_ST + 3072);

    k_transpose<<<dim3(B_, C_ / 64, N_ / 64), 256, 0, stream>>>(x, xT, conv_w, wb, st);
    k_conv<<<dim3(B_, G_, NTILES), 256, 0, stream>>>(xT, eidx, wb, y, st);
    k_bn_gelu<<<dim3((B_ * OUT_ * N_) / (256 * 8)), 256, 0, stream>>>(y, st, gamma, beta, out);
}

// Round 8
// 123.945 us; speedup vs baseline: 1.0312x; 1.0128x over previous
//
#include <hip/hip_runtime.h>
#include <hip/hip_bf16.h>
#include <math.h>

#define B_   8
#define C_   192
#define N_   3136
#define K_   9
#define OUT_ 384
#define G_   4
#define CG_  96   // in-channels per group (2C/G)
#define OG_  96   // out-channels per group
#define NTILES 49 // N_/64

typedef __attribute__((ext_vector_type(8))) short short8;
typedef __attribute__((ext_vector_type(4))) float floatx4;
typedef __attribute__((ext_vector_type(3))) unsigned int uintx3;

// ---------------- ws layout (bytes) ----------------
// xT : B*N*C   bf16 =  9,633,792
// wb : OUT*CG  bf16 =     73,728
// st : OUT*2   f32  =      3,072   (atomic-accumulated BN stats)
// y  : B*OUT*N bf16 (after st)
static const size_t OFF_XT = 0;
static const size_t OFF_WB = 9633792;
static const size_t OFF_ST = OFF_WB + 73728;

__device__ inline short f2bs(float f) {
    __hip_bfloat16 h = __float2bfloat16(f);
    union { __hip_bfloat16 h; short s; } u; u.h = h; return u.s;
}
__device__ inline float blo(unsigned int u) {
    unsigned int v = u << 16; return __builtin_bit_cast(float, v);
}
__device__ inline float bhi(unsigned int u) {
    unsigned int v = u & 0xffff0000u; return __builtin_bit_cast(float, v);
}
__device__ inline unsigned int packbf(float lo, float hi) {
    unsigned int l = (unsigned int)(unsigned short)f2bs(lo);
    unsigned int h = (unsigned int)(unsigned short)f2bs(hi);
    return (h << 16) | l;
}

// ---- Kernel A: transpose x [B,C,N] f32 -> xT [B,N,C] bf16; W->bf16; st=0 ----
// Grid (B, C/64, N/64): linear id & 7 == b, so batch b's xT is written by
// XCD b (round-robin id%8 assignment) and stays dirty in that XCD's L2 for
// k_conv, whose grid is b-aligned the same way.
__global__ __launch_bounds__(256) void k_transpose(const float* __restrict__ x,
                                                   __hip_bfloat16* __restrict__ xT,
                                                   const float* __restrict__ w,
                                                   __hip_bfloat16* __restrict__ wb,
                                                   float* __restrict__ st) {
    // weight conversion folded into 144 of the 392 y==0 blocks
    if (blockIdx.y == 0) {
        int j = blockIdx.x * NTILES + blockIdx.z;
        if (j < 144) {
            int i = j * 256 + threadIdx.x;
            wb[i] = __float2bfloat16(w[i]);
        }
    }
    // zero the atomic stats buffer (ws is re-poisoned every iteration)
    if (blockIdx.y == 1 && blockIdx.z == 0 && blockIdx.x == 0) {
        #pragma unroll
        for (int i = 0; i < 3; ++i) st[i * 256 + threadIdx.x] = 0.f;
    }
    __shared__ float tile[64][65];
    int b  = blockIdx.x;
    int cb = blockIdx.y * 64;
    int nb = blockIdx.z * 64;
    int tid = threadIdx.x;
    int tn  = tid & 63;
    int tc4 = tid >> 6;
    const float* xp = x + ((size_t)b * C_ + cb) * N_ + nb;
    #pragma unroll
    for (int i = 0; i < 16; ++i) {
        int c = tc4 + i * 4;
        tile[c][tn] = xp[(size_t)c * N_ + tn];
    }
    __syncthreads();
    __hip_bfloat16* xo = xT + ((size_t)b * N_ + nb) * C_ + cb;
    #pragma unroll
    for (int i = 0; i < 16; ++i) {
        int n = tc4 + i * 4;
        xo[(size_t)n * C_ + tn] = __float2bfloat16(tile[tn][n]);
    }
}

// ---- Kernel C: fused gather + max-rel + grouped conv + atomic BN partials ----
// R4 config (measured best: 123.9us) + XCD-batch alignment: 1-D grid with
// b = id&7. Workgroup->XCD is round-robin on linear id (id%8), so batch b
// runs ONLY on XCD b; its 1.2MB xT slice fits that XCD's 4MB L2 -> the
// random 9-neighbor gather hits L2 (~200cy) instead of ~50% L3 misses.
// (R6 had b in id/196 -- no spatial XCD pinning -- and was null; this is
// the first true test of the locality theory.)
__global__ __launch_bounds__(256, 4) void k_conv(const __hip_bfloat16* __restrict__ xT,
                                                 const int* __restrict__ eidx,
                                                 const __hip_bfloat16* __restrict__ Wb,
                                                 __hip_bfloat16* __restrict__ y,
                                                 float* __restrict__ st) {
    int id = blockIdx.x;
    int b  = id & 7;            // == XCD index under round-robin dispatch
    int g  = (id >> 3) & 3;
    int nt = id >> 5;           // 0..48
    int tid  = threadIdx.x;
    int lane = tid & 63;
    int wid  = tid >> 6;
    int n0   = nt * 64 + wid * 16;
    int col  = lane & 15;
    int quad = lane >> 4;

    __shared__ short wl[OG_ * CG_];        // 18,432 B, fragment-order swizzled
    __shared__ unsigned int xcl[64][50];   // 12,800 B, stride-50 pad
    __shared__ int eL[2][576];             //  4,608 B staged indices
    __shared__ float red[4][192];          //  3,072 B

    // ---- stage group-g weights: coalesced uint2 -> fragment-swizzled LDS ----
    const uint2* src = reinterpret_cast<const uint2*>(Wb + (size_t)g * OG_ * CG_);
    #pragma unroll
    for (int it = 0; it < 9; ++it) {
        int i  = it * 256 + tid;      // uint2 index, 2304 total
        uint2 v = src[i];
        int gs = i * 4;
        int oc = gs / CG_;
        int cg = gs - oc * CG_;
        int mt = oc >> 4, cl = oc & 15;
        int kc = cg >> 5, rem = cg & 31;
        int qd = rem >> 3, j = rem & 7;   // j in {0,4}
        int pos = (((mt * 3 + kc) * 4 + qd) * 16 + cl) * 8 + j;
        *reinterpret_cast<uint2*>(&wl[pos]) = v;
    }

    // ---- stage edge indices for this tile (coalesced) ----
    {
        const int* e0b = eidx + ((size_t)b * N_ + nt * 64) * K_;
        const int* e1b = eidx + (size_t)B_ * N_ * K_ + ((size_t)b * N_ + nt * 64) * K_;
        for (int e = tid; e < 576; e += 256) {
            eL[0][e] = e0b[e];
            eL[1][e] = e1b[e];
        }
    }
    __syncthreads();

    // ---- fused gather + max-relative into LDS xc tile ----
    // 8 lanes/node, each lane owns 3 consecutive dwords of the 24-dword slice.
    int lane8 = tid & 7;
    int slot  = tid >> 3;              // 0..31
    const unsigned int* xb =
        reinterpret_cast<const unsigned int*>(xT + (size_t)b * N_ * C_);
    int cbase = 24 * g + 3 * lane8;
    #pragma unroll
    for (int p = 0; p < 2; ++p) {
        int nloc = p * 32 + slot;      // node within tile, 0..63
        int n    = nt * 64 + nloc;
        // hoist all index reads, then batch-issue all scattered loads
        int a0[K_], a1[K_];
        #pragma unroll
        for (int k = 0; k < K_; ++k) {
            a0[k] = eL[0][nloc * 9 + k] * 96 + cbase;
            a1[k] = eL[1][nloc * 9 + k] * 96 + cbase;
        }
        uintx3 ctr = *reinterpret_cast<const uintx3*>(xb + (size_t)n * 96 + cbase);
        uintx3 vj[K_], vi[K_];
        #pragma unroll
        for (int k = 0; k < K_; ++k)
            vj[k] = *reinterpret_cast<const uintx3*>(xb + (size_t)a0[k]);
        #pragma unroll
        for (int k = 0; k < K_; ++k)
            vi[k] = *reinterpret_cast<const uintx3*>(xb + (size_t)a1[k]);
        float m0 = -INFINITY, m1 = -INFINITY, m2 = -INFINITY;
        float m3 = -INFINITY, m4 = -INFINITY, m5 = -INFINITY;
        #pragma unroll
        for (int k = 0; k < K_; ++k) {
            m0 = fmaxf(m0, blo(vj[k].x) - blo(vi[k].x));
            m1 = fmaxf(m1, bhi(vj[k].x) - bhi(vi[k].x));
            m2 = fmaxf(m2, blo(vj[k].y) - blo(vi[k].y));
            m3 = fmaxf(m3, bhi(vj[k].y) - bhi(vi[k].y));
            m4 = fmaxf(m4, blo(vj[k].z) - blo(vi[k].z));
            m5 = fmaxf(m5, bhi(vj[k].z) - bhi(vi[k].z));
        }
        unsigned int* orow = &xcl[nloc][6 * lane8];
        uint2 w0, w1, w2;
        w0.x = packbf(blo(ctr.x), m0); w0.y = packbf(bhi(ctr.x), m1);
        w1.x = packbf(blo(ctr.y), m2); w1.y = packbf(bhi(ctr.y), m3);
        w2.x = packbf(blo(ctr.z), m4); w2.y = packbf(bhi(ctr.z), m5);
        reinterpret_cast<uint2*>(orow)[0] = w0;
        reinterpret_cast<uint2*>(orow)[1] = w1;
        reinterpret_cast<uint2*>(orow)[2] = w2;
    }
    __syncthreads();

    // ---- MFMA from LDS (no bias: it cancels exactly under batch-stat BN) ----
    floatx4 acc[6];
    #pragma unroll
    for (int mt = 0; mt < 6; ++mt) acc[mt] = (floatx4){0.f, 0.f, 0.f, 0.f};
    #pragma unroll
    for (int kc = 0; kc < 3; ++kc) {
        short8 xf = *reinterpret_cast<const short8*>(
            &xcl[wid * 16 + col][kc * 16 + quad * 4]);
        #pragma unroll
        for (int mt = 0; mt < 6; ++mt) {
            short8 wf = *reinterpret_cast<const short8*>(
                &wl[(((mt * 3 + kc) * 4 + quad) * 16 + col) * 8]);
            acc[mt] = __builtin_amdgcn_mfma_f32_16x16x32_bf16(wf, xf, acc[mt], 0, 0, 0);
        }
    }

    // D layout: col(n) = lane&15, row(oc) = quad*4 + reg
    #pragma unroll
    for (int mt = 0; mt < 6; ++mt) {
        #pragma unroll
        for (int r = 0; r < 4; ++r) {
            int ol = mt * 16 + quad * 4 + r;     // oc within group, 0..95
            int oc = g * OG_ + ol;
            float v = acc[mt][r];
            y[((size_t)b * OUT_ + oc) * N_ + n0 + col] = __float2bfloat16(v);
            float s = v, ss = v * v;
            #pragma unroll
            for (int m = 1; m <= 8; m <<= 1) {
                s  += __shfl_xor(s, m);
                ss += __shfl_xor(ss, m);
            }
            if (col == 0) {
                red[wid][ol]      = s;
                red[wid][96 + ol] = ss;
            }
        }
    }
    __syncthreads();
    if (tid < 192) {
        float t = red[0][tid] + red[1][tid] + red[2][tid] + red[3][tid];
        if (tid < 96) atomicAdd(&st[g * OG_ + tid], t);
        else          atomicAdd(&st[OUT_ + g * OG_ + (tid - 96)], t);
    }
}

// ---- Kernel E: BN (batch stats) + exact GELU, 8 elems/thread ----
__global__ __launch_bounds__(256) void k_bn_gelu(const __hip_bfloat16* __restrict__ y,
                                                 const float* __restrict__ st,
                                                 const float* __restrict__ gamma,
                                                 const float* __restrict__ beta,
                                                 float* __restrict__ out) {
    size_t base = ((size_t)blockIdx.x * 256 + threadIdx.x) * 8;
    int oc = (int)((base / N_) % OUT_);       // N_ % 8 == 0 -> uniform oc per 8
    const float invM = 1.0f / (float)(B_ * N_);
    float s = st[oc], ss = st[OUT_ + oc];
    float mean = s * invM;
    float var  = ss * invM - mean * mean;
    float inv  = 1.0f / sqrtf(var + 1e-5f);
    float sc = gamma[oc] * inv;
    float sh = beta[oc] - mean * sc;

    short8 v8 = *reinterpret_cast<const short8*>(y + base);
    float4 o0, o1;
    float* op0 = &o0.x;
    float* op1 = &o1.x;
    #pragma unroll
    for (int j = 0; j < 8; ++j) {
        unsigned int u = ((unsigned int)(unsigned short)v8[j]) << 16;
        float t = __builtin_bit_cast(float, u) * sc + sh;
        float r = 0.5f * t * (1.0f + erff(t * 0.70710678118654752f));
        if (j < 4) op0[j] = r; else op1[j - 4] = r;
    }
    *reinterpret_cast<float4*>(out + base)     = o0;
    *reinterpret_cast<float4*>(out + base + 4) = o1;
}

extern "C" void kernel_launch(void* const* d_in, const int* in_sizes, int n_in,
                              void* d_out, int out_size, void* d_ws, size_t ws_size,
                              hipStream_t stream) {
    const float* x      = (const float*)d_in[0];
    const int*   eidx   = (const int*)d_in[1];
    const float* conv_w = (const float*)d_in[2];
    // d_in[3] = conv_b: unused (bias cancels exactly under batch-stat BN)
    const float* gamma  = (const float*)d_in[4];
    const float* beta   = (const float*)d_in[5];
    float* out = (float*)d_out;

    char* ws = (char*)d_ws;
    __hip_bfloat16* xT = (__hip_bfloat16*)(ws + OFF_XT);
    __hip_bfloat16* wb = (__hip_bfloat16*)(ws + OFF_WB);
    float*          st = (float*)(ws + OFF_ST);
    __hip_bfloat16* y  = (__hip_bfloat16*)(ws + OFF_ST + 3072);

    k_transpose<<<dim3(B_, C_ / 64, N_ / 64), 256, 0, stream>>>(x, xT, conv_w, wb, st);
    k_conv<<<dim3(B_ * G_ * NTILES), 256, 0, stream>>>(xT, eidx, wb, y, st);
    k_bn_gelu<<<dim3((B_ * OUT_ * N_) / (256 * 8)), 256, 0, stream>>>(y, st, gamma, beta, out);
}